// Round 12
// baseline (161.259 us; speedup 1.0000x reference)
//
#include <hip/hip_runtime.h>

// Symmetric contraction (MACE-style), N=1024 nodes, C=128 ch, D=9, S=10 species, corr=3.
//   out[n,c,i] = sum_m Uw[index[n], m, i, c] * mono_m(x[n,c,:]),  m over 219 symmetric monomials.
// Ladder: R2 static-unroll spill 1511us -> R4 runtime loop 61us (latency-bound, FETCH 42MB)
//   -> R5 XCD-local map, FETCH 10MB, but VGPR capped at 16 -> 56us -> R6 4 nodes/thread +
//   2-deep pipeline, symcon ~35-45us (below the 45us harness d_ws-poison fills in top-5).
// R7..R12 (unmeasured; 5 infra failures): symcon 1024-thr (8 mono-slices x 128c, 4 nodes/thr,
//   launch_bounds(1024,4): VGPR<=128, 2-deep pipeline -> L2-BW-bound; 4 waves/SIMD).
//   R12 edit: tree-reduce reuses TWO red buffers over 4 rounds -> static LDS 96.3 -> 59.4 KB
//   (compile-safe on any CDNA; removes the one unverified build assumption). Prep fused into
//   ONE kernel (block 0: sort+blockmap; blocks 1..140: u-symmetrize + weight fold, w in regs).

#define NMONO 219
#define NN 1024
#define NC 128
#define NS 10
#define NPB 4
#define PADBLK 272   // 8*34 >= worst-case chunk count (<=266), padded for %8 XCD layout
#define FOLD_CHUNK 16
#define NCHUNKF ((NMONO + FOLD_CHUNK - 1) / FOLD_CHUNK)   // 14

struct Tables { int mt[NMONO]; };   // (a<<8)|(b<<4)|j ; j==9 -> deg2 ; b==9 -> deg1 (sentinel)

constexpr Tables make_tables() {
    Tables T{};
    int m = 0;
    for (int a = 0; a < 9; a++)
        for (int b = a; b < 10; b++)
            for (int j = b; j < 10; j++) { T.mt[m] = (a << 8) | (b << 4) | j; m++; }
    return T;
}
__device__ __constant__ const Tables TBL = make_tables();

// Symmetrized u-sum for monomial m, slot t (0..63). Slot layout:
//   deg3: t<4 -> 0e(k=t); t<22 -> 1o(k,i); t<62 -> 2e(k,i)
//   deg2: t<2 -> 0e; t<8 -> 1o; t<23 -> 2e ;  deg1: t<9 -> [0e,1o*3,2e*5]
__device__ __forceinline__ float usum_slot(
    int m, int t,
    const float* __restrict__ u1_0e, const float* __restrict__ u1_1o, const float* __restrict__ u1_2e,
    const float* __restrict__ u2_0e, const float* __restrict__ u2_1o, const float* __restrict__ u2_2e,
    const float* __restrict__ u3_0e, const float* __restrict__ u3_1o, const float* __restrict__ u3_2e)
{
    const int e = TBL.mt[m];
    const int A = (e >> 8) & 15, B = (e >> 4) & 15, J = e & 15;
    float sv = 0.f;
    if (J < 9) {                       // deg3
        if (t < 62) {
            const float* u; int mul, idim, k, i;
            if (t < 4)       { u = u3_0e; mul = 4; idim = 1; k = t; i = 0; }
            else if (t < 22) { u = u3_1o; mul = 6; idim = 3; int r = t - 4;  k = r / 3; i = r % 3; }
            else             { u = u3_2e; mul = 8; idim = 5; int r = t - 22; k = r / 5; i = r % 5; }
            int arr[6] = { A*81+B*9+J, A*81+J*9+B, B*81+A*9+J, B*81+J*9+A, J*81+A*9+B, J*81+B*9+A };
            for (int p = 0; p < 6; p++) {
                bool dup = false;
                for (int q = 0; q < p; q++) if (arr[q] == arr[p]) dup = true;
                if (!dup) sv += u[arr[p]*(mul*idim) + k*idim + i];
            }
        }
    } else if (B < 9) {                // deg2 (A,B)
        if (t < 23) {
            const float* u; int mul, idim, k, i;
            if (t < 2)      { u = u2_0e; mul = 2; idim = 1; k = t; i = 0; }
            else if (t < 8) { u = u2_1o; mul = 2; idim = 3; int r = t - 2; k = r / 3; i = r % 3; }
            else            { u = u2_2e; mul = 3; idim = 5; int r = t - 8; k = r / 5; i = r % 5; }
            sv = u[(A*9+B)*(mul*idim) + k*idim + i];
            if (A != B) sv += u[(B*9+A)*(mul*idim) + k*idim + i];
        }
    } else {                           // deg1 (A)
        if (t < 9) {
            if (t == 0)      sv = u1_0e[A];
            else if (t < 4)  sv = u1_1o[A*3 + (t-1)];
            else             sv = u1_2e[A*5 + (t-4)];
        }
    }
    return sv;
}

// ---------- Kernel 1: prep. Block 0: species sort + XCD-local blockmap.
//            Blocks 1..140: fused u-symmetrize + weight fold (w-rows in registers). ----------
__global__ __launch_bounds__(128) void prep(
    const float* __restrict__ u1_0e, const float* __restrict__ w1_0e,
    const float* __restrict__ u1_1o, const float* __restrict__ w1_1o,
    const float* __restrict__ u1_2e, const float* __restrict__ w1_2e,
    const float* __restrict__ u2_0e, const float* __restrict__ w2_0e,
    const float* __restrict__ u2_1o, const float* __restrict__ w2_1o,
    const float* __restrict__ u2_2e, const float* __restrict__ w2_2e,
    const float* __restrict__ u3_0e, const float* __restrict__ w3_0e,
    const float* __restrict__ u3_1o, const float* __restrict__ w3_1o,
    const float* __restrict__ u3_2e, const float* __restrict__ w3_2e,
    const int* __restrict__ index,
    float* __restrict__ uwA, float* __restrict__ uwB,
    int* __restrict__ perm, int* __restrict__ offs, int* __restrict__ blockmap)
{
    const int t = threadIdx.x;

    if (blockIdx.x == 0) {
        // ----- build_groups on 128 threads -----
        __shared__ int cnt[NS], pos[NS], nbstart[NS+1];
        __shared__ int sh_nch;
        if (t < NS) cnt[t] = 0;
        __syncthreads();
        for (int n = t; n < NN; n += 128) atomicAdd(&cnt[index[n]], 1);
        __syncthreads();
        if (t == 0) {
            int o = 0, g = 0;
            for (int i = 0; i < NS; i++) {
                offs[i] = o; pos[i] = o; o += cnt[i];
                nbstart[i] = g; g += (cnt[i] + NPB - 1) / NPB;
            }
            offs[NS] = o; nbstart[NS] = g; sh_nch = g;
        }
        __syncthreads();
        const int Nch = sh_nch;
        for (int p = t; p < PADBLK; p += 128) { blockmap[2*p] = -1; blockmap[2*p+1] = 0; }
        __syncthreads();
        for (int g = t; g < Nch; g += 128) {
            const int q = Nch >> 3, r = Nch & 7;
            int x = 0, stx = 0;
            for (int xx = 0; xx < 8; xx++) {          // find XCD segment containing g
                const int cx = q + (xx < r ? 1 : 0);
                if (g < stx + cx) { x = xx; break; }
                stx += cx;
            }
            const int p = x + 8 * (g - stx);          // bijective chunk -> block position
            int sp = 0;
            while (g >= nbstart[sp+1]) sp++;
            blockmap[2*p]   = sp;
            blockmap[2*p+1] = g - nbstart[sp];
        }
        for (int n = t; n < NN; n += 128) {
            const int s = index[n];
            const int r = atomicAdd(&pos[s], 1);
            perm[r] = n;
        }
        return;
    }

    // ----- fused fold: blocks 1..NS*NCHUNKF -----
    const int b  = blockIdx.x - 1;
    const int s  = b / NCHUNKF;
    const int m0 = (b % NCHUNKF) * FOLD_CHUNK;
    __shared__ float us[FOLD_CHUNK][64];

    for (int f = t; f < FOLD_CHUNK*64; f += 128) {
        const int mm = f >> 6, sl = f & 63, m = m0 + mm;
        us[mm][sl] = (m < NMONO)
            ? usum_slot(m, sl, u1_0e, u1_1o, u1_2e, u2_0e, u2_1o, u2_2e, u3_0e, u3_1o, u3_2e)
            : 0.f;
    }
    __syncthreads();

    const int c = t;
    float W30[4], W31[6], W32[8], W20[2], W21[2], W22[3];
    #pragma unroll
    for (int k = 0; k < 4; k++) W30[k] = w3_0e[(s*4+k)*NC + c];
    #pragma unroll
    for (int k = 0; k < 6; k++) W31[k] = w3_1o[(s*6+k)*NC + c];
    #pragma unroll
    for (int k = 0; k < 8; k++) W32[k] = w3_2e[(s*8+k)*NC + c];
    #pragma unroll
    for (int k = 0; k < 2; k++) W20[k] = w2_0e[(s*2+k)*NC + c];
    #pragma unroll
    for (int k = 0; k < 2; k++) W21[k] = w2_1o[(s*2+k)*NC + c];
    #pragma unroll
    for (int k = 0; k < 3; k++) W22[k] = w2_2e[(s*3+k)*NC + c];
    const float W10 = w1_0e[s*NC + c], W11 = w1_1o[s*NC + c], W12 = w1_2e[s*NC + c];

    for (int mm = 0; mm < FOLD_CHUNK; mm++) {
        const int m = m0 + mm;
        if (m >= NMONO) break;
        const int e = TBL.mt[m];
        const int B = (e >> 4) & 15, J = e & 15;
        float o[9];
        if (J < 9) {
            float v = 0.f;
            #pragma unroll
            for (int k = 0; k < 4; k++) v += us[mm][k] * W30[k];
            o[0] = v;
            #pragma unroll
            for (int i = 0; i < 3; i++) {
                v = 0.f;
                #pragma unroll
                for (int k = 0; k < 6; k++) v += us[mm][4 + k*3 + i] * W31[k];
                o[1+i] = v;
            }
            #pragma unroll
            for (int i = 0; i < 5; i++) {
                v = 0.f;
                #pragma unroll
                for (int k = 0; k < 8; k++) v += us[mm][22 + k*5 + i] * W32[k];
                o[4+i] = v;
            }
        } else if (B < 9) {
            float v = 0.f;
            #pragma unroll
            for (int k = 0; k < 2; k++) v += us[mm][k] * W20[k];
            o[0] = v;
            #pragma unroll
            for (int i = 0; i < 3; i++) {
                v = 0.f;
                #pragma unroll
                for (int k = 0; k < 2; k++) v += us[mm][2 + k*3 + i] * W21[k];
                o[1+i] = v;
            }
            #pragma unroll
            for (int i = 0; i < 5; i++) {
                v = 0.f;
                #pragma unroll
                for (int k = 0; k < 3; k++) v += us[mm][8 + k*5 + i] * W22[k];
                o[4+i] = v;
            }
        } else {
            o[0] = us[mm][0] * W10;
            #pragma unroll
            for (int i = 0; i < 3; i++) o[1+i] = us[mm][1+i] * W11;
            #pragma unroll
            for (int i = 0; i < 5; i++) o[4+i] = us[mm][4+i] * W12;
        }
        const size_t base = (size_t)(s*NMONO + m)*NC + c;
        float4 lo; lo.x = o[0]; lo.y = o[1]; lo.z = o[2]; lo.w = o[3];
        float4 hi; hi.x = o[4]; hi.y = o[5]; hi.z = o[6]; hi.w = o[7];
        *(float4*)(uwA + base*8)     = lo;
        *(float4*)(uwA + base*8 + 4) = hi;
        uwB[base] = o[8];
    }
}

// ---------- Kernel 2: main contraction ----------
// 1024 thr = z-slice (0..7) x c (0..127); 4 nodes/thread; slice = 27-28 monomials.
// lx4[c][d][q]: 4 nodes packed -> one ds_read_b128 per index. 2-deep coeff pipeline.
// LDS: lx4 22.5 KB + red 36.9 KB = 59.4 KB static (< 64 KB, compile-safe everywhere).
#define FMA_NODE(Q, P, F0, F1, FB)                                          \
    acc[Q][0] += F0.x*(P); acc[Q][1] += F0.y*(P); acc[Q][2] += F0.z*(P);    \
    acc[Q][3] += F0.w*(P); acc[Q][4] += F1.x*(P); acc[Q][5] += F1.y*(P);    \
    acc[Q][6] += F1.z*(P); acc[Q][7] += F1.w*(P); acc[Q][8] += FB*(P);

#define CONSUME(MM, F0, F1, FB)                                             \
    { const int e = TBL.mt[MM];                                             \
      const float4 xa = *(const float4*)&lx4[c44 + ((e>>8)&15)*4];          \
      const float4 xb = *(const float4*)&lx4[c44 + ((e>>4)&15)*4];          \
      const float4 xj = *(const float4*)&lx4[c44 + (e&15)*4];               \
      FMA_NODE(0, xa.x*xb.x*xj.x, F0, F1, FB)                               \
      FMA_NODE(1, xa.y*xb.y*xj.y, F0, F1, FB)                               \
      FMA_NODE(2, xa.z*xb.z*xj.z, F0, F1, FB)                               \
      FMA_NODE(3, xa.w*xb.w*xj.w, F0, F1, FB) }

#define RED_WRITE(SLOT)                                                     \
    { float* r = &red[SLOT][c][0];                                          \
      _Pragma("unroll")                                                     \
      for (int q = 0; q < 4; q++)                                           \
          _Pragma("unroll")                                                 \
          for (int i = 0; i < 9; i++) r[q*9 + i] = acc[q][i]; }

#define RED_ADD(SLOT)                                                       \
    { const float* r = &red[SLOT][c][0];                                    \
      _Pragma("unroll")                                                     \
      for (int q = 0; q < 4; q++)                                           \
          _Pragma("unroll")                                                 \
          for (int i = 0; i < 9; i++) acc[q][i] += r[q*9 + i]; }

__global__ __launch_bounds__(1024, 4) void symcon_main(
    const float* __restrict__ x,
    const int* __restrict__ perm, const int* __restrict__ offs,
    const int* __restrict__ blockmap,
    const float* __restrict__ uwA, const float* __restrict__ uwB,
    float* __restrict__ out)
{
    __shared__ __align__(16) float lx4[128 * 44];   // [c][11 dims][4 nodes]; d=9 sentinel = 1.0
    __shared__ float red[2][128][36];               // two reduction buffers, reused over 4 rounds

    const int tid = threadIdx.x;
    const int z   = tid >> 7;        // 0..7 mono-slice
    const int c   = tid & 127;
    const int c44 = c * 44;

    const int s     = blockmap[2*blockIdx.x];
    const int chunk = blockmap[2*blockIdx.x + 1];
    if (s < 0) return;                             // block-uniform
    const int gbeg = offs[s], gend = offs[s+1];
    const int p0   = gbeg + chunk*NPB;

    int node[4]; bool valid[4];
    #pragma unroll
    for (int q = 0; q < 4; q++) {
        const int pi = p0 + q;
        valid[q] = (pi < gend);
        node[q]  = perm[valid[q] ? pi : p0];
    }

    // Stage 4 nodes' x rows (q compile-time so node[q] stays in registers).
    #pragma unroll
    for (int q = 0; q < 4; q++) {
        const size_t nb = (size_t)node[q] * 1152;
        for (int f = tid; f < 1152; f += 1024) {
            const int ch = f / 9, d = f - ch*9;
            lx4[ch*44 + d*4 + q] = x[nb + f];
        }
    }
    if (tid < 512) { const int ch = tid >> 2, q = tid & 3; lx4[ch*44 + 36 + q] = 1.0f; }
    __syncthreads();

    float acc[4][9];
    #pragma unroll
    for (int q = 0; q < 4; q++)
        #pragma unroll
        for (int i = 0; i < 9; i++) acc[q][i] = 0.f;

    // slice bounds: z<3 -> 28 monos, z>=3 -> 27  (3*28 + 5*27 = 219)
    const int mbeg = (z < 3) ? 28*z : 84 + 27*(z - 3);
    const int mend = mbeg + ((z < 3) ? 28 : 27);

    const float* pa = uwA + ((size_t)(s*NMONO + mbeg)*NC + c) * 8;
    const float* pb = uwB +  (size_t)(s*NMONO + mbeg)*NC + c;

    // 2-deep software pipeline.
    float4 A0 = *(const float4*)pa, A1 = *(const float4*)(pa + 4); float Ab = *pb;
    float4 B0 = *(const float4*)(pa + NC*8), B1 = *(const float4*)(pa + NC*8 + 4); float Bb = *(pb + NC);

    for (int m = mbeg; m < mend; m += 2) {
        const bool h2 = (m + 2 < mend), h3 = (m + 3 < mend);
        const float* ra = h2 ? pa + 2*NC*8 : pa;
        const float* rb = h2 ? pb + 2*NC   : pb;
        const float* sa = h3 ? pa + 3*NC*8 : pa;
        const float* sb = h3 ? pb + 3*NC   : pb;
        const float4 nA0 = *(const float4*)ra, nA1 = *(const float4*)(ra + 4); const float nAb = *rb;
        const float4 nB0 = *(const float4*)sa, nB1 = *(const float4*)(sa + 4); const float nBb = *sb;
        CONSUME(m, A0, A1, Ab)
        if (m + 1 < mend) { CONSUME(m + 1, B0, B1, Bb) }
        A0 = nA0; A1 = nA1; Ab = nAb;
        B0 = nB0; B1 = nB1; Bb = nBb;
        pa += 2*NC*8; pb += 2*NC;
    }

    // Reduce 8 slices into z=0 with two buffers, 4 rounds:
    //   R1: z2,z3 -> red; z0,z1 +=     (z0=z0+z2, z1=z1+z3)
    //   R2: z6,z7 -> red; z4,z5 +=     (z4=z4+z6, z5=z5+z7)
    //   R3: z4,z5 -> red; z0,z1 +=     (z0=Σeven.., z1=Σodd..)
    //   R4: z1 -> red0;  z0 += -> store
    if (z == 2 || z == 3) RED_WRITE(z - 2)
    __syncthreads();
    if (z == 0 || z == 1) RED_ADD(z)
    __syncthreads();
    if (z == 6 || z == 7) RED_WRITE(z - 6)
    __syncthreads();
    if (z == 4 || z == 5) RED_ADD(z - 4)
    __syncthreads();
    if (z == 4 || z == 5) RED_WRITE(z - 4)
    __syncthreads();
    if (z == 0 || z == 1) RED_ADD(z)
    __syncthreads();
    if (z == 1) RED_WRITE(0)
    __syncthreads();
    if (z == 0) {
        RED_ADD(0)
        #pragma unroll
        for (int q = 0; q < 4; q++) {
            if (!valid[q]) continue;
            float* orow = out + (size_t)node[q] * 1152;   // [0e: c][1o: 128+c*3+i][2e: 512+c*5+i]
            orow[c] = acc[q][0];
            #pragma unroll
            for (int i = 0; i < 3; i++) orow[128 + c*3 + i] = acc[q][1+i];
            #pragma unroll
            for (int i = 0; i < 5; i++) orow[512 + c*5 + i] = acc[q][4+i];
        }
    }
}

extern "C" void kernel_launch(void* const* d_in, const int* in_sizes, int n_in,
                              void* d_out, int out_size, void* d_ws, size_t ws_size,
                              hipStream_t stream)
{
    const float* x     = (const float*)d_in[0];
    const float* u1_0e = (const float*)d_in[1];
    const float* w1_0e = (const float*)d_in[2];
    const float* u1_1o = (const float*)d_in[3];
    const float* w1_1o = (const float*)d_in[4];
    const float* u1_2e = (const float*)d_in[5];
    const float* w1_2e = (const float*)d_in[6];
    const float* u2_0e = (const float*)d_in[7];
    const float* w2_0e = (const float*)d_in[8];
    const float* u2_1o = (const float*)d_in[9];
    const float* w2_1o = (const float*)d_in[10];
    const float* u2_2e = (const float*)d_in[11];
    const float* w2_2e = (const float*)d_in[12];
    const float* u3_0e = (const float*)d_in[13];
    const float* w3_0e = (const float*)d_in[14];
    const float* u3_1o = (const float*)d_in[15];
    const float* w3_1o = (const float*)d_in[16];
    const float* u3_2e = (const float*)d_in[17];
    const float* w3_2e = (const float*)d_in[18];
    const int*   index = (const int*)d_in[19];
    float* out = (float*)d_out;

    float* uwA = (float*)d_ws;                            // [S][219][128][8]
    float* uwB = uwA + (size_t)NS*NMONO*NC*8;             // [S][219][128]
    int*   perm     = (int*)(uwB + (size_t)NS*NMONO*NC);  // [NN]
    int*   offs     = perm + NN;                          // [NS+1]
    int*   blockmap = offs + (NS+1);                      // [PADBLK*2]

    hipLaunchKernelGGL(prep, dim3(1 + NS*NCHUNKF), dim3(128), 0, stream,
        u1_0e, w1_0e, u1_1o, w1_1o, u1_2e, w1_2e,
        u2_0e, w2_0e, u2_1o, w2_1o, u2_2e, w2_2e,
        u3_0e, w3_0e, u3_1o, w3_1o, u3_2e, w3_2e,
        index, uwA, uwB, perm, offs, blockmap);

    hipLaunchKernelGGL(symcon_main, dim3(PADBLK), dim3(1024), 0, stream,
        x, perm, offs, blockmap, uwA, uwB, out);
}

// Round 13
// 155.182 us; speedup vs baseline: 1.0392x; 1.0392x over previous
//
#include <hip/hip_runtime.h>

// Symmetric contraction (MACE-style), N=1024 nodes, C=128 ch, D=9, S=10 species, corr=3.
//   out[n,c,i] = sum_m Uw[index[n], m, i, c] * mono_m(x[n,c,:]),  m over 219 symmetric monomials.
// Ladder: R2 spill 1511us -> R4 61us latency-bound -> R5 XCD-local FETCH 10MB, 56us ->
//   R6 ~35-45us -> R12 (1024thr, 59.4KB LDS): total 161us, symcon ~30-40us — 1 block/CU and
//   ~260 blocks => TWO dispatch rounds (2nd round ~4 CUs busy) — quantization tail.
// R13 (this): symcon 512-thr blocks (4 z-slices x 128c, 4 nodes/thread, same 59.4KB LDS)
//   -> 2 blocks/CU -> 512 slots >= 272 blocks -> ONE round. Same traffic/occupancy.
//   Prep (1 kernel: block0 sort+XCD-local blockmap; blocks 1..140 u-symmetrize+w-fold) kept.

#define NMONO 219
#define NN 1024
#define NC 128
#define NS 10
#define NPB 4
#define PADBLK 272   // 8*34 >= worst-case chunk count (<=266), padded for %8 XCD layout
#define FOLD_CHUNK 16
#define NCHUNKF ((NMONO + FOLD_CHUNK - 1) / FOLD_CHUNK)   // 14

struct Tables { int mt[NMONO]; };   // (a<<8)|(b<<4)|j ; j==9 -> deg2 ; b==9 -> deg1 (sentinel)

constexpr Tables make_tables() {
    Tables T{};
    int m = 0;
    for (int a = 0; a < 9; a++)
        for (int b = a; b < 10; b++)
            for (int j = b; j < 10; j++) { T.mt[m] = (a << 8) | (b << 4) | j; m++; }
    return T;
}
__device__ __constant__ const Tables TBL = make_tables();

// Symmetrized u-sum for monomial m, slot t (0..63). Slot layout:
//   deg3: t<4 -> 0e(k=t); t<22 -> 1o(k,i); t<62 -> 2e(k,i)
//   deg2: t<2 -> 0e; t<8 -> 1o; t<23 -> 2e ;  deg1: t<9 -> [0e,1o*3,2e*5]
__device__ __forceinline__ float usum_slot(
    int m, int t,
    const float* __restrict__ u1_0e, const float* __restrict__ u1_1o, const float* __restrict__ u1_2e,
    const float* __restrict__ u2_0e, const float* __restrict__ u2_1o, const float* __restrict__ u2_2e,
    const float* __restrict__ u3_0e, const float* __restrict__ u3_1o, const float* __restrict__ u3_2e)
{
    const int e = TBL.mt[m];
    const int A = (e >> 8) & 15, B = (e >> 4) & 15, J = e & 15;
    float sv = 0.f;
    if (J < 9) {                       // deg3
        if (t < 62) {
            const float* u; int mul, idim, k, i;
            if (t < 4)       { u = u3_0e; mul = 4; idim = 1; k = t; i = 0; }
            else if (t < 22) { u = u3_1o; mul = 6; idim = 3; int r = t - 4;  k = r / 3; i = r % 3; }
            else             { u = u3_2e; mul = 8; idim = 5; int r = t - 22; k = r / 5; i = r % 5; }
            int arr[6] = { A*81+B*9+J, A*81+J*9+B, B*81+A*9+J, B*81+J*9+A, J*81+A*9+B, J*81+B*9+A };
            for (int p = 0; p < 6; p++) {
                bool dup = false;
                for (int q = 0; q < p; q++) if (arr[q] == arr[p]) dup = true;
                if (!dup) sv += u[arr[p]*(mul*idim) + k*idim + i];
            }
        }
    } else if (B < 9) {                // deg2 (A,B)
        if (t < 23) {
            const float* u; int mul, idim, k, i;
            if (t < 2)      { u = u2_0e; mul = 2; idim = 1; k = t; i = 0; }
            else if (t < 8) { u = u2_1o; mul = 2; idim = 3; int r = t - 2; k = r / 3; i = r % 3; }
            else            { u = u2_2e; mul = 3; idim = 5; int r = t - 8; k = r / 5; i = r % 5; }
            sv = u[(A*9+B)*(mul*idim) + k*idim + i];
            if (A != B) sv += u[(B*9+A)*(mul*idim) + k*idim + i];
        }
    } else {                           // deg1 (A)
        if (t < 9) {
            if (t == 0)      sv = u1_0e[A];
            else if (t < 4)  sv = u1_1o[A*3 + (t-1)];
            else             sv = u1_2e[A*5 + (t-4)];
        }
    }
    return sv;
}

// ---------- Kernel 1: prep. Block 0: species sort + XCD-local blockmap.
//            Blocks 1..140: fused u-symmetrize + weight fold (w-rows in registers). ----------
__global__ __launch_bounds__(128) void prep(
    const float* __restrict__ u1_0e, const float* __restrict__ w1_0e,
    const float* __restrict__ u1_1o, const float* __restrict__ w1_1o,
    const float* __restrict__ u1_2e, const float* __restrict__ w1_2e,
    const float* __restrict__ u2_0e, const float* __restrict__ w2_0e,
    const float* __restrict__ u2_1o, const float* __restrict__ w2_1o,
    const float* __restrict__ u2_2e, const float* __restrict__ w2_2e,
    const float* __restrict__ u3_0e, const float* __restrict__ w3_0e,
    const float* __restrict__ u3_1o, const float* __restrict__ w3_1o,
    const float* __restrict__ u3_2e, const float* __restrict__ w3_2e,
    const int* __restrict__ index,
    float* __restrict__ uwA, float* __restrict__ uwB,
    int* __restrict__ perm, int* __restrict__ offs, int* __restrict__ blockmap)
{
    const int t = threadIdx.x;

    if (blockIdx.x == 0) {
        // ----- build_groups on 128 threads -----
        __shared__ int cnt[NS], pos[NS], nbstart[NS+1];
        __shared__ int sh_nch;
        if (t < NS) cnt[t] = 0;
        __syncthreads();
        for (int n = t; n < NN; n += 128) atomicAdd(&cnt[index[n]], 1);
        __syncthreads();
        if (t == 0) {
            int o = 0, g = 0;
            for (int i = 0; i < NS; i++) {
                offs[i] = o; pos[i] = o; o += cnt[i];
                nbstart[i] = g; g += (cnt[i] + NPB - 1) / NPB;
            }
            offs[NS] = o; nbstart[NS] = g; sh_nch = g;
        }
        __syncthreads();
        const int Nch = sh_nch;
        for (int p = t; p < PADBLK; p += 128) { blockmap[2*p] = -1; blockmap[2*p+1] = 0; }
        __syncthreads();
        for (int g = t; g < Nch; g += 128) {
            const int q = Nch >> 3, r = Nch & 7;
            int x = 0, stx = 0;
            for (int xx = 0; xx < 8; xx++) {          // find XCD segment containing g
                const int cx = q + (xx < r ? 1 : 0);
                if (g < stx + cx) { x = xx; break; }
                stx += cx;
            }
            const int p = x + 8 * (g - stx);          // bijective chunk -> block position
            int sp = 0;
            while (g >= nbstart[sp+1]) sp++;
            blockmap[2*p]   = sp;
            blockmap[2*p+1] = g - nbstart[sp];
        }
        for (int n = t; n < NN; n += 128) {
            const int s = index[n];
            const int r = atomicAdd(&pos[s], 1);
            perm[r] = n;
        }
        return;
    }

    // ----- fused fold: blocks 1..NS*NCHUNKF -----
    const int b  = blockIdx.x - 1;
    const int s  = b / NCHUNKF;
    const int m0 = (b % NCHUNKF) * FOLD_CHUNK;
    __shared__ float us[FOLD_CHUNK][64];

    for (int f = t; f < FOLD_CHUNK*64; f += 128) {
        const int mm = f >> 6, sl = f & 63, m = m0 + mm;
        us[mm][sl] = (m < NMONO)
            ? usum_slot(m, sl, u1_0e, u1_1o, u1_2e, u2_0e, u2_1o, u2_2e, u3_0e, u3_1o, u3_2e)
            : 0.f;
    }
    __syncthreads();

    const int c = t;
    float W30[4], W31[6], W32[8], W20[2], W21[2], W22[3];
    #pragma unroll
    for (int k = 0; k < 4; k++) W30[k] = w3_0e[(s*4+k)*NC + c];
    #pragma unroll
    for (int k = 0; k < 6; k++) W31[k] = w3_1o[(s*6+k)*NC + c];
    #pragma unroll
    for (int k = 0; k < 8; k++) W32[k] = w3_2e[(s*8+k)*NC + c];
    #pragma unroll
    for (int k = 0; k < 2; k++) W20[k] = w2_0e[(s*2+k)*NC + c];
    #pragma unroll
    for (int k = 0; k < 2; k++) W21[k] = w2_1o[(s*2+k)*NC + c];
    #pragma unroll
    for (int k = 0; k < 3; k++) W22[k] = w2_2e[(s*3+k)*NC + c];
    const float W10 = w1_0e[s*NC + c], W11 = w1_1o[s*NC + c], W12 = w1_2e[s*NC + c];

    for (int mm = 0; mm < FOLD_CHUNK; mm++) {
        const int m = m0 + mm;
        if (m >= NMONO) break;
        const int e = TBL.mt[m];
        const int B = (e >> 4) & 15, J = e & 15;
        float o[9];
        if (J < 9) {
            float v = 0.f;
            #pragma unroll
            for (int k = 0; k < 4; k++) v += us[mm][k] * W30[k];
            o[0] = v;
            #pragma unroll
            for (int i = 0; i < 3; i++) {
                v = 0.f;
                #pragma unroll
                for (int k = 0; k < 6; k++) v += us[mm][4 + k*3 + i] * W31[k];
                o[1+i] = v;
            }
            #pragma unroll
            for (int i = 0; i < 5; i++) {
                v = 0.f;
                #pragma unroll
                for (int k = 0; k < 8; k++) v += us[mm][22 + k*5 + i] * W32[k];
                o[4+i] = v;
            }
        } else if (B < 9) {
            float v = 0.f;
            #pragma unroll
            for (int k = 0; k < 2; k++) v += us[mm][k] * W20[k];
            o[0] = v;
            #pragma unroll
            for (int i = 0; i < 3; i++) {
                v = 0.f;
                #pragma unroll
                for (int k = 0; k < 2; k++) v += us[mm][2 + k*3 + i] * W21[k];
                o[1+i] = v;
            }
            #pragma unroll
            for (int i = 0; i < 5; i++) {
                v = 0.f;
                #pragma unroll
                for (int k = 0; k < 3; k++) v += us[mm][8 + k*5 + i] * W22[k];
                o[4+i] = v;
            }
        } else {
            o[0] = us[mm][0] * W10;
            #pragma unroll
            for (int i = 0; i < 3; i++) o[1+i] = us[mm][1+i] * W11;
            #pragma unroll
            for (int i = 0; i < 5; i++) o[4+i] = us[mm][4+i] * W12;
        }
        const size_t base = (size_t)(s*NMONO + m)*NC + c;
        float4 lo; lo.x = o[0]; lo.y = o[1]; lo.z = o[2]; lo.w = o[3];
        float4 hi; hi.x = o[4]; hi.y = o[5]; hi.z = o[6]; hi.w = o[7];
        *(float4*)(uwA + base*8)     = lo;
        *(float4*)(uwA + base*8 + 4) = hi;
        uwB[base] = o[8];
    }
}

// ---------- Kernel 2: main contraction ----------
// 512 thr = z-slice (0..3) x c (0..127); 4 nodes/thread; slice = 54-55 monomials.
// lx4[c][d][q]: 4 nodes packed -> one ds_read_b128 per index. 2-deep coeff pipeline.
// LDS: lx4 22.5 KB + red 36.9 KB = 59.4 KB -> 2 blocks/CU -> 512 slots >= 272 blocks: ONE round.
#define FMA_NODE(Q, P, F0, F1, FB)                                          \
    acc[Q][0] += F0.x*(P); acc[Q][1] += F0.y*(P); acc[Q][2] += F0.z*(P);    \
    acc[Q][3] += F0.w*(P); acc[Q][4] += F1.x*(P); acc[Q][5] += F1.y*(P);    \
    acc[Q][6] += F1.z*(P); acc[Q][7] += F1.w*(P); acc[Q][8] += FB*(P);

#define CONSUME(MM, F0, F1, FB)                                             \
    { const int e = TBL.mt[MM];                                             \
      const float4 xa = *(const float4*)&lx4[c44 + ((e>>8)&15)*4];          \
      const float4 xb = *(const float4*)&lx4[c44 + ((e>>4)&15)*4];          \
      const float4 xj = *(const float4*)&lx4[c44 + (e&15)*4];               \
      FMA_NODE(0, xa.x*xb.x*xj.x, F0, F1, FB)                               \
      FMA_NODE(1, xa.y*xb.y*xj.y, F0, F1, FB)                               \
      FMA_NODE(2, xa.z*xb.z*xj.z, F0, F1, FB)                               \
      FMA_NODE(3, xa.w*xb.w*xj.w, F0, F1, FB) }

#define RED_WRITE(SLOT)                                                     \
    { float* r = &red[SLOT][c][0];                                          \
      _Pragma("unroll")                                                     \
      for (int q = 0; q < 4; q++)                                           \
          _Pragma("unroll")                                                 \
          for (int i = 0; i < 9; i++) r[q*9 + i] = acc[q][i]; }

#define RED_ADD(SLOT)                                                       \
    { const float* r = &red[SLOT][c][0];                                    \
      _Pragma("unroll")                                                     \
      for (int q = 0; q < 4; q++)                                           \
          _Pragma("unroll")                                                 \
          for (int i = 0; i < 9; i++) acc[q][i] += r[q*9 + i]; }

__global__ __launch_bounds__(512, 4) void symcon_main(
    const float* __restrict__ x,
    const int* __restrict__ perm, const int* __restrict__ offs,
    const int* __restrict__ blockmap,
    const float* __restrict__ uwA, const float* __restrict__ uwB,
    float* __restrict__ out)
{
    __shared__ __align__(16) float lx4[128 * 44];   // [c][11 dims][4 nodes]; d=9 sentinel = 1.0
    __shared__ float red[2][128][36];               // two reduction buffers (2 rounds)

    const int tid = threadIdx.x;
    const int z   = tid >> 7;        // 0..3 mono-slice
    const int c   = tid & 127;
    const int c44 = c * 44;

    const int s     = blockmap[2*blockIdx.x];
    const int chunk = blockmap[2*blockIdx.x + 1];
    if (s < 0) return;                             // block-uniform
    const int gbeg = offs[s], gend = offs[s+1];
    const int p0   = gbeg + chunk*NPB;

    int node[4]; bool valid[4];
    #pragma unroll
    for (int q = 0; q < 4; q++) {
        const int pi = p0 + q;
        valid[q] = (pi < gend);
        node[q]  = perm[valid[q] ? pi : p0];
    }

    // Stage 4 nodes' x rows (q compile-time so node[q] stays in registers).
    #pragma unroll
    for (int q = 0; q < 4; q++) {
        const size_t nb = (size_t)node[q] * 1152;
        for (int f = tid; f < 1152; f += 512) {
            const int ch = f / 9, d = f - ch*9;
            lx4[ch*44 + d*4 + q] = x[nb + f];
        }
    }
    { const int ch = tid >> 2, q = tid & 3; lx4[ch*44 + 36 + q] = 1.0f; }   // 512 thr = 128x4
    __syncthreads();

    float acc[4][9];
    #pragma unroll
    for (int q = 0; q < 4; q++)
        #pragma unroll
        for (int i = 0; i < 9; i++) acc[q][i] = 0.f;

    // slice bounds: z<3 -> 55 monos, z==3 -> 54  (3*55 + 54 = 219)
    const int mbeg = 55 * z;
    const int mend = (z == 3) ? NMONO : mbeg + 55;

    const float* pa = uwA + ((size_t)(s*NMONO + mbeg)*NC + c) * 8;
    const float* pb = uwB +  (size_t)(s*NMONO + mbeg)*NC + c;

    // 2-deep software pipeline.
    float4 A0 = *(const float4*)pa, A1 = *(const float4*)(pa + 4); float Ab = *pb;
    float4 B0 = *(const float4*)(pa + NC*8), B1 = *(const float4*)(pa + NC*8 + 4); float Bb = *(pb + NC);

    for (int m = mbeg; m < mend; m += 2) {
        const bool h2 = (m + 2 < mend), h3 = (m + 3 < mend);
        const float* ra = h2 ? pa + 2*NC*8 : pa;
        const float* rb = h2 ? pb + 2*NC   : pb;
        const float* sa = h3 ? pa + 3*NC*8 : pa;
        const float* sb = h3 ? pb + 3*NC   : pb;
        const float4 nA0 = *(const float4*)ra, nA1 = *(const float4*)(ra + 4); const float nAb = *rb;
        const float4 nB0 = *(const float4*)sa, nB1 = *(const float4*)(sa + 4); const float nBb = *sb;
        CONSUME(m, A0, A1, Ab)
        if (m + 1 < mend) { CONSUME(m + 1, B0, B1, Bb) }
        A0 = nA0; A1 = nA1; Ab = nAb;
        B0 = nB0; B1 = nB1; Bb = nBb;
        pa += 2*NC*8; pb += 2*NC;
    }

    // Reduce 4 slices into z=0 with two buffers, 2 rounds:
    //   R1: z2,z3 -> red[0],red[1]; z0,z1 +=
    //   R2: z1 -> red[0]; z0 += -> store
    if (z == 2 || z == 3) RED_WRITE(z - 2)
    __syncthreads();
    if (z == 0 || z == 1) RED_ADD(z)
    __syncthreads();
    if (z == 1) RED_WRITE(0)
    __syncthreads();
    if (z == 0) {
        RED_ADD(0)
        #pragma unroll
        for (int q = 0; q < 4; q++) {
            if (!valid[q]) continue;
            float* orow = out + (size_t)node[q] * 1152;   // [0e: c][1o: 128+c*3+i][2e: 512+c*5+i]
            orow[c] = acc[q][0];
            #pragma unroll
            for (int i = 0; i < 3; i++) orow[128 + c*3 + i] = acc[q][1+i];
            #pragma unroll
            for (int i = 0; i < 5; i++) orow[512 + c*5 + i] = acc[q][4+i];
        }
    }
}

extern "C" void kernel_launch(void* const* d_in, const int* in_sizes, int n_in,
                              void* d_out, int out_size, void* d_ws, size_t ws_size,
                              hipStream_t stream)
{
    const float* x     = (const float*)d_in[0];
    const float* u1_0e = (const float*)d_in[1];
    const float* w1_0e = (const float*)d_in[2];
    const float* u1_1o = (const float*)d_in[3];
    const float* w1_1o = (const float*)d_in[4];
    const float* u1_2e = (const float*)d_in[5];
    const float* w1_2e = (const float*)d_in[6];
    const float* u2_0e = (const float*)d_in[7];
    const float* w2_0e = (const float*)d_in[8];
    const float* u2_1o = (const float*)d_in[9];
    const float* w2_1o = (const float*)d_in[10];
    const float* u2_2e = (const float*)d_in[11];
    const float* w2_2e = (const float*)d_in[12];
    const float* u3_0e = (const float*)d_in[13];
    const float* w3_0e = (const float*)d_in[14];
    const float* u3_1o = (const float*)d_in[15];
    const float* w3_1o = (const float*)d_in[16];
    const float* u3_2e = (const float*)d_in[17];
    const float* w3_2e = (const float*)d_in[18];
    const int*   index = (const int*)d_in[19];
    float* out = (float*)d_out;

    float* uwA = (float*)d_ws;                            // [S][219][128][8]
    float* uwB = uwA + (size_t)NS*NMONO*NC*8;             // [S][219][128]
    int*   perm     = (int*)(uwB + (size_t)NS*NMONO*NC);  // [NN]
    int*   offs     = perm + NN;                          // [NS+1]
    int*   blockmap = offs + (NS+1);                      // [PADBLK*2]

    hipLaunchKernelGGL(prep, dim3(1 + NS*NCHUNKF), dim3(128), 0, stream,
        u1_0e, w1_0e, u1_1o, w1_1o, u1_2e, w1_2e,
        u2_0e, w2_0e, u2_1o, w2_1o, u2_2e, w2_2e,
        u3_0e, w3_0e, u3_1o, w3_1o, u3_2e, w3_2e,
        index, uwA, uwB, perm, offs, blockmap);

    hipLaunchKernelGGL(symcon_main, dim3(PADBLK), dim3(512), 0, stream,
        x, perm, offs, blockmap, uwA, uwB, out);
}

// Round 14
// 153.637 us; speedup vs baseline: 1.0496x; 1.0101x over previous
//
#include <hip/hip_runtime.h>

// Symmetric contraction (MACE-style), N=1024 nodes, C=128 ch, D=9, S=10 species, corr=3.
//   out[n,c,i] = sum_m Uw[index[n], m, i, c] * mono_m(x[n,c,:]),  m over 219 symmetric monomials.
// Ladder: R2 spill 1511us -> R4 61us -> R5 56us (XCD-local, FETCH 10MB) -> R6 149.5 (split prep)
//   -> R12 161 (fused prep, 2-round symcon) -> R13 155 (1-round symcon).
// Harness floor ~95-100us (256MiB d_ws 0xAA poison = 45us fill + restores + gaps, in timed path).
// R14 (this): prep re-SPLIT (R13's fused prep recomputed u-sums 10x across species, ~30-40us):
//   Kernel A usym_build: 219 blocks compute each mono's symmetrized u-sum ONCE (64 slots ||),
//     block 219 does species sort + XCD-local blockmap.  Kernel B uw_fold: pure-FMA fold,
//     w-rows in regs, usum from global.  symcon byte-identical to R13 (512thr, NPB=4, 1 round).

#define NMONO 219
#define NN 1024
#define NC 128
#define NS 10
#define NPB 4
#define PADBLK 272   // 8*34 >= worst-case chunk count (<=266), padded for %8 XCD layout
#define FOLD_CHUNK 16
#define NCHUNKF ((NMONO + FOLD_CHUNK - 1) / FOLD_CHUNK)   // 14

struct Tables { int mt[NMONO]; };   // (a<<8)|(b<<4)|j ; j==9 -> deg2 ; b==9 -> deg1 (sentinel)

constexpr Tables make_tables() {
    Tables T{};
    int m = 0;
    for (int a = 0; a < 9; a++)
        for (int b = a; b < 10; b++)
            for (int j = b; j < 10; j++) { T.mt[m] = (a << 8) | (b << 4) | j; m++; }
    return T;
}
__device__ __constant__ const Tables TBL = make_tables();

// ---------- Kernel A: blocks 0..218 -> symmetrized u-sum for one mono (64 slots in parallel);
//            block 219 -> species counting-sort + XCD-local blockmap. ----------
// Slot layout (64 per mono):
//   deg3: t<4 -> 0e(k=t); t<22 -> 1o(k,i); t<62 -> 2e(k,i)
//   deg2: t<2 -> 0e; t<8 -> 1o; t<23 -> 2e ;  deg1: t<9 -> [0e,1o*3,2e*5]
__global__ __launch_bounds__(64) void usym_build(
    const float* __restrict__ u1_0e, const float* __restrict__ u1_1o, const float* __restrict__ u1_2e,
    const float* __restrict__ u2_0e, const float* __restrict__ u2_1o, const float* __restrict__ u2_2e,
    const float* __restrict__ u3_0e, const float* __restrict__ u3_1o, const float* __restrict__ u3_2e,
    const int* __restrict__ index,
    float* __restrict__ usumAll,   // [NMONO][64]
    int* __restrict__ perm, int* __restrict__ offs, int* __restrict__ blockmap)
{
    const int t = threadIdx.x;

    if (blockIdx.x == NMONO) {
        // ----- build_groups on 64 threads (one wave) -----
        __shared__ int cnt[NS], pos[NS], nbstart[NS+1];
        __shared__ int sh_nch;
        if (t < NS) cnt[t] = 0;
        __syncthreads();
        for (int n = t; n < NN; n += 64) atomicAdd(&cnt[index[n]], 1);
        __syncthreads();
        if (t == 0) {
            int o = 0, g = 0;
            for (int i = 0; i < NS; i++) {
                offs[i] = o; pos[i] = o; o += cnt[i];
                nbstart[i] = g; g += (cnt[i] + NPB - 1) / NPB;
            }
            offs[NS] = o; nbstart[NS] = g; sh_nch = g;
        }
        __syncthreads();
        const int Nch = sh_nch;
        for (int p = t; p < PADBLK; p += 64) { blockmap[2*p] = -1; blockmap[2*p+1] = 0; }
        __syncthreads();
        for (int g = t; g < Nch; g += 64) {
            const int q = Nch >> 3, r = Nch & 7;
            int x = 0, stx = 0;
            for (int xx = 0; xx < 8; xx++) {          // find XCD segment containing g
                const int cx = q + (xx < r ? 1 : 0);
                if (g < stx + cx) { x = xx; break; }
                stx += cx;
            }
            const int p = x + 8 * (g - stx);          // bijective chunk -> block position
            int sp = 0;
            while (g >= nbstart[sp+1]) sp++;
            blockmap[2*p]   = sp;
            blockmap[2*p+1] = g - nbstart[sp];
        }
        for (int n = t; n < NN; n += 64) {
            const int s = index[n];
            const int r = atomicAdd(&pos[s], 1);
            perm[r] = n;
        }
        return;
    }

    // ----- u-sum for monomial blockIdx.x -----
    const int m = blockIdx.x;
    const int e = TBL.mt[m];
    const int A = (e >> 8) & 15, B = (e >> 4) & 15, J = e & 15;
    float sv = 0.f;
    if (J < 9) {                       // deg3
        if (t < 62) {
            const float* u; int mul, idim, k, i;
            if (t < 4)       { u = u3_0e; mul = 4; idim = 1; k = t; i = 0; }
            else if (t < 22) { u = u3_1o; mul = 6; idim = 3; int r = t - 4;  k = r / 3; i = r % 3; }
            else             { u = u3_2e; mul = 8; idim = 5; int r = t - 22; k = r / 5; i = r % 5; }
            int arr[6] = { A*81+B*9+J, A*81+J*9+B, B*81+A*9+J, B*81+J*9+A, J*81+A*9+B, J*81+B*9+A };
            for (int p = 0; p < 6; p++) {
                bool dup = false;
                for (int q = 0; q < p; q++) if (arr[q] == arr[p]) dup = true;
                if (!dup) sv += u[arr[p]*(mul*idim) + k*idim + i];
            }
        }
    } else if (B < 9) {                // deg2 (A,B)
        if (t < 23) {
            const float* u; int mul, idim, k, i;
            if (t < 2)      { u = u2_0e; mul = 2; idim = 1; k = t; i = 0; }
            else if (t < 8) { u = u2_1o; mul = 2; idim = 3; int r = t - 2; k = r / 3; i = r % 3; }
            else            { u = u2_2e; mul = 3; idim = 5; int r = t - 8; k = r / 5; i = r % 5; }
            sv = u[(A*9+B)*(mul*idim) + k*idim + i];
            if (A != B) sv += u[(B*9+A)*(mul*idim) + k*idim + i];
        }
    } else {                           // deg1 (A)
        if (t < 9) {
            if (t == 0)      sv = u1_0e[A];
            else if (t < 4)  sv = u1_1o[A*3 + (t-1)];
            else             sv = u1_2e[A*5 + (t-4)];
        }
    }
    usumAll[m*64 + t] = sv;
}

// ---------- Kernel B: fold usum with per-species weights (w-rows in registers, pure FMA). ----------
__global__ __launch_bounds__(128) void uw_fold(
    const float* __restrict__ w1_0e, const float* __restrict__ w1_1o, const float* __restrict__ w1_2e,
    const float* __restrict__ w2_0e, const float* __restrict__ w2_1o, const float* __restrict__ w2_2e,
    const float* __restrict__ w3_0e, const float* __restrict__ w3_1o, const float* __restrict__ w3_2e,
    const float* __restrict__ usumAll,
    float* __restrict__ uwA, float* __restrict__ uwB)
{
    const int s  = blockIdx.x / NCHUNKF;
    const int m0 = (blockIdx.x % NCHUNKF) * FOLD_CHUNK;
    const int c  = threadIdx.x;
    __shared__ float us[FOLD_CHUNK][64];

    for (int f = c; f < FOLD_CHUNK*64; f += 128) {
        const int mm = f >> 6, sl = f & 63, m = m0 + mm;
        us[mm][sl] = (m < NMONO) ? usumAll[m*64 + sl] : 0.f;
    }
    __syncthreads();

    float W30[4], W31[6], W32[8], W20[2], W21[2], W22[3];
    #pragma unroll
    for (int k = 0; k < 4; k++) W30[k] = w3_0e[(s*4+k)*NC + c];
    #pragma unroll
    for (int k = 0; k < 6; k++) W31[k] = w3_1o[(s*6+k)*NC + c];
    #pragma unroll
    for (int k = 0; k < 8; k++) W32[k] = w3_2e[(s*8+k)*NC + c];
    #pragma unroll
    for (int k = 0; k < 2; k++) W20[k] = w2_0e[(s*2+k)*NC + c];
    #pragma unroll
    for (int k = 0; k < 2; k++) W21[k] = w2_1o[(s*2+k)*NC + c];
    #pragma unroll
    for (int k = 0; k < 3; k++) W22[k] = w2_2e[(s*3+k)*NC + c];
    const float W10 = w1_0e[s*NC + c], W11 = w1_1o[s*NC + c], W12 = w1_2e[s*NC + c];

    for (int mm = 0; mm < FOLD_CHUNK; mm++) {
        const int m = m0 + mm;
        if (m >= NMONO) break;
        const int e = TBL.mt[m];
        const int B = (e >> 4) & 15, J = e & 15;
        float o[9];
        if (J < 9) {
            float v = 0.f;
            #pragma unroll
            for (int k = 0; k < 4; k++) v += us[mm][k] * W30[k];
            o[0] = v;
            #pragma unroll
            for (int i = 0; i < 3; i++) {
                v = 0.f;
                #pragma unroll
                for (int k = 0; k < 6; k++) v += us[mm][4 + k*3 + i] * W31[k];
                o[1+i] = v;
            }
            #pragma unroll
            for (int i = 0; i < 5; i++) {
                v = 0.f;
                #pragma unroll
                for (int k = 0; k < 8; k++) v += us[mm][22 + k*5 + i] * W32[k];
                o[4+i] = v;
            }
        } else if (B < 9) {
            float v = 0.f;
            #pragma unroll
            for (int k = 0; k < 2; k++) v += us[mm][k] * W20[k];
            o[0] = v;
            #pragma unroll
            for (int i = 0; i < 3; i++) {
                v = 0.f;
                #pragma unroll
                for (int k = 0; k < 2; k++) v += us[mm][2 + k*3 + i] * W21[k];
                o[1+i] = v;
            }
            #pragma unroll
            for (int i = 0; i < 5; i++) {
                v = 0.f;
                #pragma unroll
                for (int k = 0; k < 3; k++) v += us[mm][8 + k*5 + i] * W22[k];
                o[4+i] = v;
            }
        } else {
            o[0] = us[mm][0] * W10;
            #pragma unroll
            for (int i = 0; i < 3; i++) o[1+i] = us[mm][1+i] * W11;
            #pragma unroll
            for (int i = 0; i < 5; i++) o[4+i] = us[mm][4+i] * W12;
        }
        const size_t base = (size_t)(s*NMONO + m)*NC + c;
        float4 lo; lo.x = o[0]; lo.y = o[1]; lo.z = o[2]; lo.w = o[3];
        float4 hi; hi.x = o[4]; hi.y = o[5]; hi.z = o[6]; hi.w = o[7];
        *(float4*)(uwA + base*8)     = lo;
        *(float4*)(uwA + base*8 + 4) = hi;
        uwB[base] = o[8];
    }
}

// ---------- Kernel C: main contraction (byte-identical to R13) ----------
// 512 thr = z-slice (0..3) x c (0..127); 4 nodes/thread; slice = 54-55 monomials.
// lx4[c][d][q]: 4 nodes packed -> one ds_read_b128 per index. 2-deep coeff pipeline.
// LDS 59.4 KB -> 2 blocks/CU -> 512 slots >= 272 blocks: ONE dispatch round.
#define FMA_NODE(Q, P, F0, F1, FB)                                          \
    acc[Q][0] += F0.x*(P); acc[Q][1] += F0.y*(P); acc[Q][2] += F0.z*(P);    \
    acc[Q][3] += F0.w*(P); acc[Q][4] += F1.x*(P); acc[Q][5] += F1.y*(P);    \
    acc[Q][6] += F1.z*(P); acc[Q][7] += F1.w*(P); acc[Q][8] += FB*(P);

#define CONSUME(MM, F0, F1, FB)                                             \
    { const int e = TBL.mt[MM];                                             \
      const float4 xa = *(const float4*)&lx4[c44 + ((e>>8)&15)*4];          \
      const float4 xb = *(const float4*)&lx4[c44 + ((e>>4)&15)*4];          \
      const float4 xj = *(const float4*)&lx4[c44 + (e&15)*4];               \
      FMA_NODE(0, xa.x*xb.x*xj.x, F0, F1, FB)                               \
      FMA_NODE(1, xa.y*xb.y*xj.y, F0, F1, FB)                               \
      FMA_NODE(2, xa.z*xb.z*xj.z, F0, F1, FB)                               \
      FMA_NODE(3, xa.w*xb.w*xj.w, F0, F1, FB) }

#define RED_WRITE(SLOT)                                                     \
    { float* r = &red[SLOT][c][0];                                          \
      _Pragma("unroll")                                                     \
      for (int q = 0; q < 4; q++)                                           \
          _Pragma("unroll")                                                 \
          for (int i = 0; i < 9; i++) r[q*9 + i] = acc[q][i]; }

#define RED_ADD(SLOT)                                                       \
    { const float* r = &red[SLOT][c][0];                                    \
      _Pragma("unroll")                                                     \
      for (int q = 0; q < 4; q++)                                           \
          _Pragma("unroll")                                                 \
          for (int i = 0; i < 9; i++) acc[q][i] += r[q*9 + i]; }

__global__ __launch_bounds__(512, 4) void symcon_main(
    const float* __restrict__ x,
    const int* __restrict__ perm, const int* __restrict__ offs,
    const int* __restrict__ blockmap,
    const float* __restrict__ uwA, const float* __restrict__ uwB,
    float* __restrict__ out)
{
    __shared__ __align__(16) float lx4[128 * 44];   // [c][11 dims][4 nodes]; d=9 sentinel = 1.0
    __shared__ float red[2][128][36];               // two reduction buffers (2 rounds)

    const int tid = threadIdx.x;
    const int z   = tid >> 7;        // 0..3 mono-slice
    const int c   = tid & 127;
    const int c44 = c * 44;

    const int s     = blockmap[2*blockIdx.x];
    const int chunk = blockmap[2*blockIdx.x + 1];
    if (s < 0) return;                             // block-uniform
    const int gbeg = offs[s], gend = offs[s+1];
    const int p0   = gbeg + chunk*NPB;

    int node[4]; bool valid[4];
    #pragma unroll
    for (int q = 0; q < 4; q++) {
        const int pi = p0 + q;
        valid[q] = (pi < gend);
        node[q]  = perm[valid[q] ? pi : p0];
    }

    // Stage 4 nodes' x rows (q compile-time so node[q] stays in registers).
    #pragma unroll
    for (int q = 0; q < 4; q++) {
        const size_t nb = (size_t)node[q] * 1152;
        for (int f = tid; f < 1152; f += 512) {
            const int ch = f / 9, d = f - ch*9;
            lx4[ch*44 + d*4 + q] = x[nb + f];
        }
    }
    { const int ch = tid >> 2, q = tid & 3; lx4[ch*44 + 36 + q] = 1.0f; }   // 512 thr = 128x4
    __syncthreads();

    float acc[4][9];
    #pragma unroll
    for (int q = 0; q < 4; q++)
        #pragma unroll
        for (int i = 0; i < 9; i++) acc[q][i] = 0.f;

    // slice bounds: z<3 -> 55 monos, z==3 -> 54  (3*55 + 54 = 219)
    const int mbeg = 55 * z;
    const int mend = (z == 3) ? NMONO : mbeg + 55;

    const float* pa = uwA + ((size_t)(s*NMONO + mbeg)*NC + c) * 8;
    const float* pb = uwB +  (size_t)(s*NMONO + mbeg)*NC + c;

    // 2-deep software pipeline.
    float4 A0 = *(const float4*)pa, A1 = *(const float4*)(pa + 4); float Ab = *pb;
    float4 B0 = *(const float4*)(pa + NC*8), B1 = *(const float4*)(pa + NC*8 + 4); float Bb = *(pb + NC);

    for (int m = mbeg; m < mend; m += 2) {
        const bool h2 = (m + 2 < mend), h3 = (m + 3 < mend);
        const float* ra = h2 ? pa + 2*NC*8 : pa;
        const float* rb = h2 ? pb + 2*NC   : pb;
        const float* sa = h3 ? pa + 3*NC*8 : pa;
        const float* sb = h3 ? pb + 3*NC   : pb;
        const float4 nA0 = *(const float4*)ra, nA1 = *(const float4*)(ra + 4); const float nAb = *rb;
        const float4 nB0 = *(const float4*)sa, nB1 = *(const float4*)(sa + 4); const float nBb = *sb;
        CONSUME(m, A0, A1, Ab)
        if (m + 1 < mend) { CONSUME(m + 1, B0, B1, Bb) }
        A0 = nA0; A1 = nA1; Ab = nAb;
        B0 = nB0; B1 = nB1; Bb = nBb;
        pa += 2*NC*8; pb += 2*NC;
    }

    // Reduce 4 slices into z=0 with two buffers, 2 rounds.
    if (z == 2 || z == 3) RED_WRITE(z - 2)
    __syncthreads();
    if (z == 0 || z == 1) RED_ADD(z)
    __syncthreads();
    if (z == 1) RED_WRITE(0)
    __syncthreads();
    if (z == 0) {
        RED_ADD(0)
        #pragma unroll
        for (int q = 0; q < 4; q++) {
            if (!valid[q]) continue;
            float* orow = out + (size_t)node[q] * 1152;   // [0e: c][1o: 128+c*3+i][2e: 512+c*5+i]
            orow[c] = acc[q][0];
            #pragma unroll
            for (int i = 0; i < 3; i++) orow[128 + c*3 + i] = acc[q][1+i];
            #pragma unroll
            for (int i = 0; i < 5; i++) orow[512 + c*5 + i] = acc[q][4+i];
        }
    }
}

extern "C" void kernel_launch(void* const* d_in, const int* in_sizes, int n_in,
                              void* d_out, int out_size, void* d_ws, size_t ws_size,
                              hipStream_t stream)
{
    const float* x     = (const float*)d_in[0];
    const float* u1_0e = (const float*)d_in[1];
    const float* w1_0e = (const float*)d_in[2];
    const float* u1_1o = (const float*)d_in[3];
    const float* w1_1o = (const float*)d_in[4];
    const float* u1_2e = (const float*)d_in[5];
    const float* w1_2e = (const float*)d_in[6];
    const float* u2_0e = (const float*)d_in[7];
    const float* w2_0e = (const float*)d_in[8];
    const float* u2_1o = (const float*)d_in[9];
    const float* w2_1o = (const float*)d_in[10];
    const float* u2_2e = (const float*)d_in[11];
    const float* w2_2e = (const float*)d_in[12];
    const float* u3_0e = (const float*)d_in[13];
    const float* w3_0e = (const float*)d_in[14];
    const float* u3_1o = (const float*)d_in[15];
    const float* w3_1o = (const float*)d_in[16];
    const float* u3_2e = (const float*)d_in[17];
    const float* w3_2e = (const float*)d_in[18];
    const int*   index = (const int*)d_in[19];
    float* out = (float*)d_out;

    float* uwA     = (float*)d_ws;                        // [S][219][128][8]
    float* uwB     = uwA + (size_t)NS*NMONO*NC*8;         // [S][219][128]
    float* usumAll = uwB + (size_t)NS*NMONO*NC;           // [219][64]
    int*   perm     = (int*)(usumAll + NMONO*64);         // [NN]
    int*   offs     = perm + NN;                          // [NS+1]
    int*   blockmap = offs + (NS+1);                      // [PADBLK*2]

    hipLaunchKernelGGL(usym_build, dim3(NMONO + 1), dim3(64), 0, stream,
        u1_0e, u1_1o, u1_2e, u2_0e, u2_1o, u2_2e, u3_0e, u3_1o, u3_2e,
        index, usumAll, perm, offs, blockmap);

    hipLaunchKernelGGL(uw_fold, dim3(NS*NCHUNKF), dim3(128), 0, stream,
        w1_0e, w1_1o, w1_2e, w2_0e, w2_1o, w2_2e, w3_0e, w3_1o, w3_2e,
        usumAll, uwA, uwB);

    hipLaunchKernelGGL(symcon_main, dim3(PADBLK), dim3(512), 0, stream,
        x, perm, offs, blockmap, uwA, uwB, out);
}